// Round 9
// baseline (140.816 us; speedup 1.0000x reference)
//
#include <hip/hip_runtime.h>
#include <cstdint>
#include <cstddef>

// ---------------------------------------------------------------------------
// MHA forward: x[2,2048,1024] fp32, wqkv[3072,1024], wo[1024,1024], wo_b[1024]
// out = concat(y[2,2048,1024], k[2,16,2048,64], v[2,16,2048,64]) fp32
// Pipeline: cvt->bf16 (fused); QKV GEMM (256x256 deep-pipeline, counted vmcnt,
// pre-scales Q by softmax scale); flash causal attn (QBLK=128: 4 waves x 32 q
// amortize K/V LDS reads 2x — LDS-BW-bound fix; swapped-QK^T + cvt_pk P);
// proj GEMM (128x128 m97-structure).
// ---------------------------------------------------------------------------

using bf16x8 = __attribute__((ext_vector_type(8))) __bf16;
using f32x4  = __attribute__((ext_vector_type(4))) float;
using u16    = unsigned short;

#define SOFT_SCALE 0.1803368801111244f   // 0.125 * log2(e)  (attn in exp2 domain)

// fp32 -> bf16 bits, round-to-nearest-even
__device__ __forceinline__ u16 f2bf(float f) {
  union { float f; uint32_t u; } a; a.f = f;
  uint32_t r = a.u + 0x7fffu + ((a.u >> 16) & 1u);
  return (u16)(r >> 16);
}

__device__ __forceinline__ bf16x8 ldfrag(const u16* p) {
  return *reinterpret_cast<const bf16x8*>(p);
}

__device__ __forceinline__ void gload_lds16(const void* g, void* l) {
  __builtin_amdgcn_global_load_lds((const __attribute__((address_space(1))) void*)g,
                                   (__attribute__((address_space(3))) void*)l,
                                   16, 0, 0);
}

// pack two fp32 -> one u32 of two bf16 (lo = a, hi = b), RNE
__device__ __forceinline__ uint32_t cvt_pk_bf16(float a, float b) {
  uint32_t r;
  asm("v_cvt_pk_bf16_f32 %0, %1, %2" : "=v"(r) : "v"(a), "v"(b));
  return r;
}

// ---------------------------------------------------------------------------
// fused fp32 -> bf16 convert for x, wqkv, wo (single launch)
// ---------------------------------------------------------------------------
__global__ void cvt_all(const float* __restrict__ x, const float* __restrict__ wqkv,
                        const float* __restrict__ wo,
                        u16* __restrict__ xb, u16* __restrict__ wqkvb, u16* __restrict__ wob) {
  int i = blockIdx.x * blockDim.x + threadIdx.x;
  int stride = gridDim.x * blockDim.x;
  for (; i < 2097152; i += stride) {
    const float* src; u16* dst; int j;
    if (i < 1048576)      { src = x;    dst = xb;    j = i; }
    else if (i < 1835008) { src = wqkv; dst = wqkvb; j = i - 1048576; }
    else                  { src = wo;   dst = wob;   j = i - 1835008; }
    float4 v = reinterpret_cast<const float4*>(src)[j];
    ushort4 o;
    o.x = f2bf(v.x); o.y = f2bf(v.y); o.z = f2bf(v.z); o.w = f2bf(v.w);
    reinterpret_cast<ushort4*>(dst)[j] = o;
  }
}

// ---------------------------------------------------------------------------
// QKV GEMM, deep-pipelined: X[4096][1024] x Wqkv[3072][1024]^T, tile 256x256.
// (validated round 6; Q output now pre-scaled by SOFT_SCALE)
// ---------------------------------------------------------------------------
__global__ __launch_bounds__(512, 2) void qkv_gemm_kernel(
    const u16* __restrict__ Xb, const u16* __restrict__ Wb,
    u16* __restrict__ Qws, u16* __restrict__ Kws, u16* __restrict__ Vtws,
    float* __restrict__ out) {
  extern __shared__ char smem[];   // [2][32KB] A then [2][32KB] B

  const int tid = threadIdx.x, lane = tid & 63, wid = tid >> 6;
  const int wr = wid >> 2, wc = wid & 3;
  const int fq = lane >> 4, fr = lane & 15;

  const int wg = (blockIdx.x & 7) * 24 + (blockIdx.x >> 3);
  const int bm = wg / 12, bn = wg % 12;
  const int m0 = bm * 256, n0 = bn * 256;

  const char* Ab = (const char*)Xb + (size_t)m0 * 2048;
  const char* Bb = (const char*)Wb + (size_t)n0 * 2048;

  f32x4 acc[8][4] = {};

  auto stage = [&](int t, int cc) {
    char* As = smem + cc * 32768;
    char* Bs = smem + 65536 + cc * 32768;
#pragma unroll
    for (int f = 0; f < 4; ++f) {
      int lin = (f * 512 + tid) * 16;
      int row = lin >> 7;
      int col = (lin & 127) ^ ((row & 7) << 4);
      gload_lds16(Ab + (size_t)row * 2048 + t * 128 + col, As + lin);
      gload_lds16(Bb + (size_t)row * 2048 + t * 128 + col, Bs + lin);
    }
  };

  stage(0, 0);
  int cur = 0;
  for (int t = 0; t < 16; ++t) {
    if (t < 15) {
      stage(t + 1, cur ^ 1);
      asm volatile("s_waitcnt vmcnt(8)" ::: "memory");
    } else {
      asm volatile("s_waitcnt vmcnt(0)" ::: "memory");
    }
    __builtin_amdgcn_s_barrier();
    __builtin_amdgcn_sched_barrier(0);

    const char* As = smem + cur * 32768;
    const char* Bs = smem + 65536 + cur * 32768;

#pragma unroll
    for (int ks = 0; ks < 2; ++ks) {
      bf16x8 af[8];
#pragma unroll
      for (int m = 0; m < 8; ++m) {
        int row = wr * 128 + m * 16 + fr;
        int col = (ks * 64 + fq * 16) ^ ((row & 7) << 4);
        af[m] = *(const bf16x8*)(As + row * 128 + col);
      }
#pragma unroll
      for (int nh = 0; nh < 2; ++nh) {
        int row0 = wc * 64 + (nh * 2) * 16 + fr;
        int col0 = (ks * 64 + fq * 16) ^ ((row0 & 7) << 4);
        bf16x8 bf0 = *(const bf16x8*)(Bs + row0 * 128 + col0);
        int row1 = wc * 64 + (nh * 2 + 1) * 16 + fr;
        int col1 = (ks * 64 + fq * 16) ^ ((row1 & 7) << 4);
        bf16x8 bf1 = *(const bf16x8*)(Bs + row1 * 128 + col1);
        __builtin_amdgcn_s_setprio(1);
#pragma unroll
        for (int m = 0; m < 8; ++m) {
          acc[m][nh * 2]     = __builtin_amdgcn_mfma_f32_16x16x32_bf16(af[m], bf0, acc[m][nh * 2], 0, 0, 0);
          acc[m][nh * 2 + 1] = __builtin_amdgcn_mfma_f32_16x16x32_bf16(af[m], bf1, acc[m][nh * 2 + 1], 0, 0, 0);
        }
        __builtin_amdgcn_s_setprio(0);
      }
    }
    asm volatile("s_waitcnt lgkmcnt(0)" ::: "memory");
    __builtin_amdgcn_s_barrier();
    cur ^= 1;
  }

  const int sect = n0 >> 10;
  const int nn0 = (n0 & 1023) + wc * 64;
  const int mbase = m0 + wr * 128;
#pragma unroll
  for (int m = 0; m < 8; ++m)
#pragma unroll
    for (int n = 0; n < 4; ++n) {
      int mB = mbase + m * 16 + fq * 4;
      int ncol = nn0 + n * 16 + fr;
      int b = mB >> 11, s0 = mB & 2047;
      int h = ncol >> 6, hd = ncol & 63;
      size_t base = (((size_t)b * 16 + h) * 2048 + s0) * 64 + hd;
      float v0 = acc[m][n][0], v1 = acc[m][n][1], v2 = acc[m][n][2], v3 = acc[m][n][3];
      if (sect == 0) {
        // Q pre-scaled by softmax scale (attn then uses exp2 directly)
        Qws[base]       = f2bf(v0 * SOFT_SCALE);
        Qws[base + 64]  = f2bf(v1 * SOFT_SCALE);
        Qws[base + 128] = f2bf(v2 * SOFT_SCALE);
        Qws[base + 192] = f2bf(v3 * SOFT_SCALE);
      } else if (sect == 1) {
        Kws[base] = f2bf(v0); Kws[base + 64] = f2bf(v1);
        Kws[base + 128] = f2bf(v2); Kws[base + 192] = f2bf(v3);
        out[4194304 + base] = v0; out[4194304 + base + 64] = v1;
        out[4194304 + base + 128] = v2; out[4194304 + base + 192] = v3;
      } else {
        out[8388608 + base] = v0; out[8388608 + base + 64] = v1;
        out[8388608 + base + 128] = v2; out[8388608 + base + 192] = v3;
        size_t tt = ((size_t)(b * 16 + h) * 64 + hd) * 2048 + s0;
        ushort4 pk; pk.x = f2bf(v0); pk.y = f2bf(v1); pk.z = f2bf(v2); pk.w = f2bf(v3);
        *reinterpret_cast<ushort4*>(Vtws + tt) = pk;
      }
    }
}

// ---------------------------------------------------------------------------
// 128x128 tile GEMM core (m97 structure) — used by proj only.
// ---------------------------------------------------------------------------
__device__ __forceinline__ void gemm128_core(const u16* __restrict__ A,
                                             const u16* __restrict__ B,
                                             int m0, int n0, int K,
                                             u16* As, u16* Bs, f32x4 acc[4][4]) {
  const int tid  = threadIdx.x;
  const int lane = tid & 63;
  const int wid  = tid >> 6;
  const int wr = wid >> 1, wc = wid & 1;
  const int fq = lane >> 4, fr = lane & 15;

  for (int kb = 0; kb < K; kb += 32) {
#pragma unroll
    for (int j = 0; j < 2; ++j) {
      int lin = (j * 256 + tid) * 16;
      int row = lin >> 6;
      int rb  = lin & 63;
      gload_lds16((const char*)(A + (size_t)(m0 + row) * K + kb) + rb, (char*)As + lin);
      gload_lds16((const char*)(B + (size_t)(n0 + row) * K + kb) + rb, (char*)Bs + lin);
    }
    __syncthreads();

    bf16x8 av[4], bv[4];
#pragma unroll
    for (int i = 0; i < 4; ++i) av[i] = ldfrag(As + (wr * 64 + i * 16 + fr) * 32 + fq * 8);
#pragma unroll
    for (int j = 0; j < 4; ++j) bv[j] = ldfrag(Bs + (wc * 64 + j * 16 + fr) * 32 + fq * 8);
    __builtin_amdgcn_s_setprio(1);
#pragma unroll
    for (int i = 0; i < 4; ++i)
#pragma unroll
      for (int j = 0; j < 4; ++j)
        acc[i][j] = __builtin_amdgcn_mfma_f32_16x16x32_bf16(av[i], bv[j], acc[i][j], 0, 0, 0);
    __builtin_amdgcn_s_setprio(0);
    __syncthreads();
  }
}

// ---------------------------------------------------------------------------
// Flash causal attention. grid = 16 q-blocks x 32 bh = 512; block = 256.
// QBLK=128: 4 waves x 32 q-rows (2 MFMA q-groups each) — K/V fragments loaded
// once per wave per KV tile, reused for both q-groups (halves LDS-BW/q).
// KVBLK=64, [64][64] XOR-swizzled K/V^T dbuf (r6-proven). Swapped QK^T,
// cvt_pk packed P, scalar ssum, no-max softmax (Q pre-scaled upstream).
// ---------------------------------------------------------------------------
__global__ __launch_bounds__(256) void attn_kernel(
    const u16* __restrict__ Qw, const u16* __restrict__ Kw,
    const u16* __restrict__ Vtw, u16* __restrict__ Ow) {
  __shared__ u16 Ks[2][64 * 64];
  __shared__ u16 Vs[2][64 * 64];
  __shared__ u16 Ps[4 * 32 * 64];   // per-wave P [q=32][kv=64], 128B rows, swz

  const int tid = threadIdx.x, lane = tid & 63, wid = tid >> 6;
  const int fq = lane >> 4, fr = lane & 15;
  const int bh = blockIdx.x & 31;
  const int qb = 15 - (blockIdx.x >> 5);   // heavy blocks first
  const int b = bh >> 4, h = bh & 15;
  const int q0 = qb * 128;
  const int qwbase = q0 + wid * 32;        // wave's first q row

  const u16* Qbase  = Qw  + (size_t)bh * 2048 * 64;
  const u16* Kbase  = Kw  + (size_t)bh * 2048 * 64;
  const char* VtBase = (const char*)(Vtw + (size_t)bh * 64 * 2048);
  char* PswB = (char*)(Ps + wid * 2048);

  // stage KV tile kt: K [64][64] swizzled + V^T [64][64] swizzled
  auto stageKV = [&](int kt, int cc) {
#pragma unroll
    for (int f = 0; f < 2; ++f) {
      int lin = (f * 256 + tid) * 16;
      int row = lin >> 7;
      int logical = lin ^ ((row & 7) << 4);
      gload_lds16((const char*)Kbase + (size_t)kt * 8192 + logical, (char*)Ks[cc] + lin);
      gload_lds16(VtBase + (size_t)row * 4096 + (size_t)kt * 128 + (logical & 127),
                  (char*)Vs[cc] + lin);
    }
  };

  stageKV(0, 0);

  // Q B-frags for 2 q-groups x 2 k-halves (Q pre-scaled by SOFT_SCALE)
  bf16x8 qa[2][2];
#pragma unroll
  for (int qg = 0; qg < 2; ++qg)
#pragma unroll
    for (int hh = 0; hh < 2; ++hh)
      qa[qg][hh] = ldfrag(Qbase + (size_t)(qwbase + qg * 16 + fr) * 64 + hh * 32 + fq * 8);

  float ssum[2] = {0.f, 0.f};   // per q-group, row q = qwbase+qg*16+fr
  f32x4 accO[2][4] = {};

  const int ktiles = 2 * qb + 2;
  int cur = 0;
  for (int kt = 0; kt < ktiles; ++kt) {
    __syncthreads();   // buf[cur] staged; all waves past prev reads

    if (kt + 1 < ktiles) stageKV(kt + 1, cur ^ 1);

    // wave-uniform skip: this wave's q-rows don't reach this KV tile
    if (kt * 64 <= qwbase + 31) {
      const u16* Kc = Ks[cur];
      const u16* Vc = Vs[cur];

      // ---- S^T = K Q^T: lane gets S[q=...+fr][kv=n*16+fq*4+r] per qg
      f32x4 sfr[2][4];
      __builtin_amdgcn_s_setprio(1);
#pragma unroll
      for (int n = 0; n < 4; ++n) {
        int krow = n * 16 + fr;
        bf16x8 kf0 = ldfrag(Kc + krow * 64 + ((fq * 8)      ^ ((krow & 7) << 3)));
        bf16x8 kf1 = ldfrag(Kc + krow * 64 + ((fq * 8 + 32) ^ ((krow & 7) << 3)));
#pragma unroll
        for (int qg = 0; qg < 2; ++qg) {
          f32x4 z = {};
          z = __builtin_amdgcn_mfma_f32_16x16x32_bf16(kf0, qa[qg][0], z, 0, 0, 0);
          z = __builtin_amdgcn_mfma_f32_16x16x32_bf16(kf1, qa[qg][1], z, 0, 0, 0);
          sfr[qg][n] = z;
        }
      }
      __builtin_amdgcn_s_setprio(0);

      // ---- p = exp2(s); mask only on the (peeled) diagonal tiles
      const bool diag = (kt >= 2 * qb);
#pragma unroll
      for (int qg = 0; qg < 2; ++qg) {
        int qrow = qwbase + qg * 16 + fr;
#pragma unroll
        for (int n = 0; n < 4; ++n) {
          float p0, p1, p2, p3;
          if (!diag) {
            p0 = exp2f(sfr[qg][n][0]);
            p1 = exp2f(sfr[qg][n][1]);
            p2 = exp2f(sfr[qg][n][2]);
            p3 = exp2f(sfr[qg][n][3]);
          } else {
            int kvg = kt * 64 + n * 16 + fq * 4;
            p0 = (kvg + 0 > qrow) ? 0.f : exp2f(sfr[qg][n][0]);
            p1 = (kvg + 1 > qrow) ? 0.f : exp2f(sfr[qg][n][1]);
            p2 = (kvg + 2 > qrow) ? 0.f : exp2f(sfr[qg][n][2]);
            p3 = (kvg + 3 > qrow) ? 0.f : exp2f(sfr[qg][n][3]);
          }
          ssum[qg] += (p0 + p1) + (p2 + p3);
          uint2 w;
          w.x = cvt_pk_bf16(p0, p1);
          w.y = cvt_pk_bf16(p2, p3);
          int prow = qg * 16 + fr;
          *reinterpret_cast<uint2*>(PswB + prow * 128 + ((n * 32 + fq * 8) ^ ((prow & 7) << 4))) = w;
        }
      }

      // ---- O += P V : pa[qg] rows = qg*16+fr; V-frags shared across qg
      bf16x8 pa0[2], pa1[2];
#pragma unroll
      for (int qg = 0; qg < 2; ++qg) {
        int prow = qg * 16 + fr;
        pa0[qg] = *(const bf16x8*)(PswB + prow * 128 + ((fq * 16)      ^ ((prow & 7) << 4)));
        pa1[qg] = *(const bf16x8*)(PswB + prow * 128 + ((fq * 16 + 64) ^ ((prow & 7) << 4)));
      }
      __builtin_amdgcn_s_setprio(1);
#pragma unroll
      for (int nh = 0; nh < 4; ++nh) {
        int vrow = nh * 16 + fr;
        bf16x8 vb0 = ldfrag(Vc + vrow * 64 + ((fq * 8)      ^ ((vrow & 7) << 3)));
        bf16x8 vb1 = ldfrag(Vc + vrow * 64 + ((fq * 8 + 32) ^ ((vrow & 7) << 3)));
#pragma unroll
        for (int qg = 0; qg < 2; ++qg) {
          accO[qg][nh] = __builtin_amdgcn_mfma_f32_16x16x32_bf16(pa0[qg], vb0, accO[qg][nh], 0, 0, 0);
          accO[qg][nh] = __builtin_amdgcn_mfma_f32_16x16x32_bf16(pa1[qg], vb1, accO[qg][nh], 0, 0, 0);
        }
      }
      __builtin_amdgcn_s_setprio(0);
    }
    cur ^= 1;
  }

  // ---- finalize: sum the 4 fq copies of each q-row, invert, redistribute
  float invq[2][4];
#pragma unroll
  for (int qg = 0; qg < 2; ++qg) {
    float s = ssum[qg];
    s += __shfl_xor(s, 16);
    s += __shfl_xor(s, 32);
    float inv = 1.0f / s;            // for q-row = qwbase + qg*16 + fr
#pragma unroll
    for (int r = 0; r < 4; ++r) invq[qg][r] = __shfl(inv, fq * 4 + r);
  }

  // ---- epilogue: O[q=qwbase+qg*16+fq*4+r][hd=nh*16+fr] -> [b,s,(h,hd)] bf16
#pragma unroll
  for (int qg = 0; qg < 2; ++qg)
#pragma unroll
    for (int nh = 0; nh < 4; ++nh)
#pragma unroll
      for (int r = 0; r < 4; ++r) {
        float o = accO[qg][nh][r] * invq[qg][r];
        int qr = qwbase + qg * 16 + fq * 4 + r;
        Ow[((size_t)b * 2048 + qr) * 1024 + h * 64 + nh * 16 + fr] = f2bf(o);
      }
}

// ---------------------------------------------------------------------------
// Output projection: O[4096][1024] x Wo[1024][1024]^T + b -> y fp32
// ---------------------------------------------------------------------------
__global__ __launch_bounds__(256) void proj_gemm_kernel(
    const u16* __restrict__ Ob, const u16* __restrict__ Wob,
    const float* __restrict__ bias, float* __restrict__ out) {
  __shared__ u16 As[128 * 32];
  __shared__ u16 Bs[128 * 32];
  const int NB = 8;
  int m0 = (blockIdx.x / NB) * 128, n0 = (blockIdx.x % NB) * 128;
  f32x4 acc[4][4] = {};
  gemm128_core(Ob, Wob, m0, n0, 1024, As, Bs, acc);

  const int lane = threadIdx.x & 63, wid = threadIdx.x >> 6;
  const int wr = wid >> 1, wc = wid & 1, fq = lane >> 4, fr = lane & 15;
#pragma unroll
  for (int i = 0; i < 4; ++i)
#pragma unroll
    for (int j = 0; j < 4; ++j)
#pragma unroll
      for (int r = 0; r < 4; ++r) {
        int m = m0 + wr * 64 + i * 16 + fq * 4 + r;
        int n = n0 + wc * 64 + j * 16 + fr;
        out[(size_t)m * 1024 + n] = acc[i][j][r] + bias[n];
      }
}

// ---------------------------------------------------------------------------
extern "C" void kernel_launch(void* const* d_in, const int* in_sizes, int n_in,
                              void* d_out, int out_size, void* d_ws, size_t ws_size,
                              hipStream_t stream) {
  const float* x    = (const float*)d_in[0];
  const float* wqkv = (const float*)d_in[1];
  const float* wo   = (const float*)d_in[2];
  const float* wo_b = (const float*)d_in[3];
  float* out = (float*)d_out;

  u16* xb    = (u16*)d_ws;            // 4096*1024
  u16* wqkvb = xb    + 4194304;       // 3072*1024
  u16* wob   = wqkvb + 3145728;       // 1024*1024
  u16* q_ws  = wob   + 1048576;       // [2,16,2048,64] (pre-scaled)
  u16* k_ws  = q_ws  + 4194304;       // [2,16,2048,64]
  u16* vt_ws = k_ws  + 4194304;       // [2,16,64,2048]  (V^T)
  u16* o_ws  = vt_ws + 4194304;       // [4096,1024]

  static bool attr_set = false;
  if (!attr_set) {
    hipFuncSetAttribute((const void*)qkv_gemm_kernel,
                        hipFuncAttributeMaxDynamicSharedMemorySize, 131072);
    attr_set = true;
  }

  cvt_all<<<2048, 256, 0, stream>>>(x, wqkv, wo, xb, wqkvb, wob);
  qkv_gemm_kernel<<<192, 512, 131072, stream>>>(xb, wqkvb, q_ws, k_ws, vt_ws, out);
  attn_kernel<<<16 * 32, 256, 0, stream>>>(q_ws, k_ws, vt_ws, o_ws);
  proj_gemm_kernel<<<32 * 8, 256, 0, stream>>>(o_ws, wob, wo_b, out);
}

// Round 10
// 119.081 us; speedup vs baseline: 1.1825x; 1.1825x over previous
//
#include <hip/hip_runtime.h>
#include <cstdint>
#include <cstddef>

// ---------------------------------------------------------------------------
// MHA forward: x[2,2048,1024] fp32, wqkv[3072,1024], wo[1024,1024], wo_b[1024]
// out = concat(y[2,2048,1024], k[2,16,2048,64], v[2,16,2048,64]) fp32
// Pipeline: cvt->bf16 (fused); QKV GEMM (256x256 deep-pipeline, counted vmcnt,
// Q pre-scaled); flash causal attn (r8 skeleton + in-register P via
// permlane16/32_swap: no P LDS round-trip, 32KB LDS -> 4 blocks/CU);
// proj GEMM (128x128 m97-structure).
// ---------------------------------------------------------------------------

using bf16x8 = __attribute__((ext_vector_type(8))) __bf16;
using f32x4  = __attribute__((ext_vector_type(4))) float;
using u16    = unsigned short;

#define SOFT_SCALE 0.1803368801111244f   // 0.125 * log2(e)  (attn in exp2 domain)

// fp32 -> bf16 bits, round-to-nearest-even
__device__ __forceinline__ u16 f2bf(float f) {
  union { float f; uint32_t u; } a; a.f = f;
  uint32_t r = a.u + 0x7fffu + ((a.u >> 16) & 1u);
  return (u16)(r >> 16);
}

__device__ __forceinline__ bf16x8 ldfrag(const u16* p) {
  return *reinterpret_cast<const bf16x8*>(p);
}

__device__ __forceinline__ void gload_lds16(const void* g, void* l) {
  __builtin_amdgcn_global_load_lds((const __attribute__((address_space(1))) void*)g,
                                   (__attribute__((address_space(3))) void*)l,
                                   16, 0, 0);
}

// pack two fp32 -> one u32 of two bf16 (lo = a, hi = b), RNE
__device__ __forceinline__ uint32_t cvt_pk_bf16(float a, float b) {
  uint32_t r;
  asm("v_cvt_pk_bf16_f32 %0, %1, %2" : "=v"(r) : "v"(a), "v"(b));
  return r;
}

// ---------------------------------------------------------------------------
// fused fp32 -> bf16 convert for x, wqkv, wo (single launch)
// ---------------------------------------------------------------------------
__global__ void cvt_all(const float* __restrict__ x, const float* __restrict__ wqkv,
                        const float* __restrict__ wo,
                        u16* __restrict__ xb, u16* __restrict__ wqkvb, u16* __restrict__ wob) {
  int i = blockIdx.x * blockDim.x + threadIdx.x;
  int stride = gridDim.x * blockDim.x;
  for (; i < 2097152; i += stride) {
    const float* src; u16* dst; int j;
    if (i < 1048576)      { src = x;    dst = xb;    j = i; }
    else if (i < 1835008) { src = wqkv; dst = wqkvb; j = i - 1048576; }
    else                  { src = wo;   dst = wob;   j = i - 1835008; }
    float4 v = reinterpret_cast<const float4*>(src)[j];
    ushort4 o;
    o.x = f2bf(v.x); o.y = f2bf(v.y); o.z = f2bf(v.z); o.w = f2bf(v.w);
    reinterpret_cast<ushort4*>(dst)[j] = o;
  }
}

// ---------------------------------------------------------------------------
// QKV GEMM, deep-pipelined: X[4096][1024] x Wqkv[3072][1024]^T, tile 256x256.
// (validated round 6; Q output pre-scaled by SOFT_SCALE — validated round 9)
// ---------------------------------------------------------------------------
__global__ __launch_bounds__(512, 2) void qkv_gemm_kernel(
    const u16* __restrict__ Xb, const u16* __restrict__ Wb,
    u16* __restrict__ Qws, u16* __restrict__ Kws, u16* __restrict__ Vtws,
    float* __restrict__ out) {
  extern __shared__ char smem[];   // [2][32KB] A then [2][32KB] B

  const int tid = threadIdx.x, lane = tid & 63, wid = tid >> 6;
  const int wr = wid >> 2, wc = wid & 3;
  const int fq = lane >> 4, fr = lane & 15;

  const int wg = (blockIdx.x & 7) * 24 + (blockIdx.x >> 3);
  const int bm = wg / 12, bn = wg % 12;
  const int m0 = bm * 256, n0 = bn * 256;

  const char* Ab = (const char*)Xb + (size_t)m0 * 2048;
  const char* Bb = (const char*)Wb + (size_t)n0 * 2048;

  f32x4 acc[8][4] = {};

  auto stage = [&](int t, int cc) {
    char* As = smem + cc * 32768;
    char* Bs = smem + 65536 + cc * 32768;
#pragma unroll
    for (int f = 0; f < 4; ++f) {
      int lin = (f * 512 + tid) * 16;
      int row = lin >> 7;
      int col = (lin & 127) ^ ((row & 7) << 4);
      gload_lds16(Ab + (size_t)row * 2048 + t * 128 + col, As + lin);
      gload_lds16(Bb + (size_t)row * 2048 + t * 128 + col, Bs + lin);
    }
  };

  stage(0, 0);
  int cur = 0;
  for (int t = 0; t < 16; ++t) {
    if (t < 15) {
      stage(t + 1, cur ^ 1);
      asm volatile("s_waitcnt vmcnt(8)" ::: "memory");
    } else {
      asm volatile("s_waitcnt vmcnt(0)" ::: "memory");
    }
    __builtin_amdgcn_s_barrier();
    __builtin_amdgcn_sched_barrier(0);

    const char* As = smem + cur * 32768;
    const char* Bs = smem + 65536 + cur * 32768;

#pragma unroll
    for (int ks = 0; ks < 2; ++ks) {
      bf16x8 af[8];
#pragma unroll
      for (int m = 0; m < 8; ++m) {
        int row = wr * 128 + m * 16 + fr;
        int col = (ks * 64 + fq * 16) ^ ((row & 7) << 4);
        af[m] = *(const bf16x8*)(As + row * 128 + col);
      }
#pragma unroll
      for (int nh = 0; nh < 2; ++nh) {
        int row0 = wc * 64 + (nh * 2) * 16 + fr;
        int col0 = (ks * 64 + fq * 16) ^ ((row0 & 7) << 4);
        bf16x8 bf0 = *(const bf16x8*)(Bs + row0 * 128 + col0);
        int row1 = wc * 64 + (nh * 2 + 1) * 16 + fr;
        int col1 = (ks * 64 + fq * 16) ^ ((row1 & 7) << 4);
        bf16x8 bf1 = *(const bf16x8*)(Bs + row1 * 128 + col1);
        __builtin_amdgcn_s_setprio(1);
#pragma unroll
        for (int m = 0; m < 8; ++m) {
          acc[m][nh * 2]     = __builtin_amdgcn_mfma_f32_16x16x32_bf16(af[m], bf0, acc[m][nh * 2], 0, 0, 0);
          acc[m][nh * 2 + 1] = __builtin_amdgcn_mfma_f32_16x16x32_bf16(af[m], bf1, acc[m][nh * 2 + 1], 0, 0, 0);
        }
        __builtin_amdgcn_s_setprio(0);
      }
    }
    asm volatile("s_waitcnt lgkmcnt(0)" ::: "memory");
    __builtin_amdgcn_s_barrier();
    cur ^= 1;
  }

  const int sect = n0 >> 10;
  const int nn0 = (n0 & 1023) + wc * 64;
  const int mbase = m0 + wr * 128;
#pragma unroll
  for (int m = 0; m < 8; ++m)
#pragma unroll
    for (int n = 0; n < 4; ++n) {
      int mB = mbase + m * 16 + fq * 4;
      int ncol = nn0 + n * 16 + fr;
      int b = mB >> 11, s0 = mB & 2047;
      int h = ncol >> 6, hd = ncol & 63;
      size_t base = (((size_t)b * 16 + h) * 2048 + s0) * 64 + hd;
      float v0 = acc[m][n][0], v1 = acc[m][n][1], v2 = acc[m][n][2], v3 = acc[m][n][3];
      if (sect == 0) {
        // Q pre-scaled by softmax scale (attn then uses exp2 directly)
        Qws[base]       = f2bf(v0 * SOFT_SCALE);
        Qws[base + 64]  = f2bf(v1 * SOFT_SCALE);
        Qws[base + 128] = f2bf(v2 * SOFT_SCALE);
        Qws[base + 192] = f2bf(v3 * SOFT_SCALE);
      } else if (sect == 1) {
        Kws[base] = f2bf(v0); Kws[base + 64] = f2bf(v1);
        Kws[base + 128] = f2bf(v2); Kws[base + 192] = f2bf(v3);
        out[4194304 + base] = v0; out[4194304 + base + 64] = v1;
        out[4194304 + base + 128] = v2; out[4194304 + base + 192] = v3;
      } else {
        out[8388608 + base] = v0; out[8388608 + base + 64] = v1;
        out[8388608 + base + 128] = v2; out[8388608 + base + 192] = v3;
        size_t tt = ((size_t)(b * 16 + h) * 64 + hd) * 2048 + s0;
        ushort4 pk; pk.x = f2bf(v0); pk.y = f2bf(v1); pk.z = f2bf(v2); pk.w = f2bf(v3);
        *reinterpret_cast<ushort4*>(Vtws + tt) = pk;
      }
    }
}

// ---------------------------------------------------------------------------
// 128x128 tile GEMM core (m97 structure) — used by proj only.
// ---------------------------------------------------------------------------
__device__ __forceinline__ void gemm128_core(const u16* __restrict__ A,
                                             const u16* __restrict__ B,
                                             int m0, int n0, int K,
                                             u16* As, u16* Bs, f32x4 acc[4][4]) {
  const int tid  = threadIdx.x;
  const int lane = tid & 63;
  const int wid  = tid >> 6;
  const int wr = wid >> 1, wc = wid & 1;
  const int fq = lane >> 4, fr = lane & 15;

  for (int kb = 0; kb < K; kb += 32) {
#pragma unroll
    for (int j = 0; j < 2; ++j) {
      int lin = (j * 256 + tid) * 16;
      int row = lin >> 6;
      int rb  = lin & 63;
      gload_lds16((const char*)(A + (size_t)(m0 + row) * K + kb) + rb, (char*)As + lin);
      gload_lds16((const char*)(B + (size_t)(n0 + row) * K + kb) + rb, (char*)Bs + lin);
    }
    __syncthreads();

    bf16x8 av[4], bv[4];
#pragma unroll
    for (int i = 0; i < 4; ++i) av[i] = ldfrag(As + (wr * 64 + i * 16 + fr) * 32 + fq * 8);
#pragma unroll
    for (int j = 0; j < 4; ++j) bv[j] = ldfrag(Bs + (wc * 64 + j * 16 + fr) * 32 + fq * 8);
    __builtin_amdgcn_s_setprio(1);
#pragma unroll
    for (int i = 0; i < 4; ++i)
#pragma unroll
      for (int j = 0; j < 4; ++j)
        acc[i][j] = __builtin_amdgcn_mfma_f32_16x16x32_bf16(av[i], bv[j], acc[i][j], 0, 0, 0);
    __builtin_amdgcn_s_setprio(0);
    __syncthreads();
  }
}

// ---------------------------------------------------------------------------
// Flash causal attention. grid = 32 q-blocks x 32 bh = 1024; block = 256.
// r8 skeleton: QBLK=64 (4 waves x 16 q), KVBLK=64, [64][64] XOR-swizzled
// K/V^T dbuf. Swapped QK^T -> P lane-local; cvt_pk + permlane32/16_swap
// redistribute P into the PV A-fragment IN REGISTERS (no P LDS).
// LDS 32KB -> 4-5 blocks/CU. No-max softmax (Q pre-scaled), scalar ssum.
// ---------------------------------------------------------------------------
__global__ __launch_bounds__(256, 4) void attn_kernel(
    const u16* __restrict__ Qw, const u16* __restrict__ Kw,
    const u16* __restrict__ Vtw, u16* __restrict__ Ow) {
  __shared__ u16 Ks[2][64 * 64];
  __shared__ u16 Vs[2][64 * 64];

  const int tid = threadIdx.x, lane = tid & 63, wid = tid >> 6;
  const int fq = lane >> 4, fr = lane & 15;
  const int bh = blockIdx.x & 31;
  const int qb = 31 - (blockIdx.x >> 5);   // heavy blocks first
  const int b = bh >> 4, h = bh & 15;
  const int q0 = qb * 64;

  const u16* Qbase  = Qw  + (size_t)bh * 2048 * 64;
  const u16* Kbase  = Kw  + (size_t)bh * 2048 * 64;
  const char* VtBase = (const char*)(Vtw + (size_t)bh * 64 * 2048);

  // ---- prologue: stage KV tile 0 into buffer 0 (inverse-swizzled source)
#pragma unroll
  for (int f = 0; f < 2; ++f) {
    int lin = (f * 256 + tid) * 16;
    int row = lin >> 7;
    int logical = lin ^ ((row & 7) << 4);
    gload_lds16((const char*)Kbase + logical, (char*)Ks[0] + lin);
    gload_lds16(VtBase + (size_t)row * 4096 + (logical & 127), (char*)Vs[0] + lin);
  }

  // ---- Q fragments: wave's 16 q-rows, q = fr (pre-scaled upstream)
  const int qrow = q0 + wid * 16 + fr;
  bf16x8 qa0 = ldfrag(Qbase + (size_t)qrow * 64 + fq * 8);
  bf16x8 qa1 = ldfrag(Qbase + (size_t)qrow * 64 + 32 + fq * 8);

  float ssum = 0.f;        // partial row sum for q = fr
  f32x4 accO[4] = {};

  int cur = 0;
  for (int kb = 0; kb <= qb; ++kb) {
    __syncthreads();   // buf[cur] staged; all waves past prev reads

    if (kb < qb) {
      const char* kg = (const char*)(Kbase + (size_t)(kb + 1) * 64 * 64);
#pragma unroll
      for (int f = 0; f < 2; ++f) {
        int lin = (f * 256 + tid) * 16;
        int row = lin >> 7;
        int logical = lin ^ ((row & 7) << 4);
        gload_lds16(kg + logical, (char*)Ks[cur ^ 1] + lin);
        gload_lds16(VtBase + (size_t)row * 4096 + (size_t)(kb + 1) * 128 + (logical & 127),
                    (char*)Vs[cur ^ 1] + lin);
      }
    }

    const u16* Kc = Ks[cur];
    const u16* Vc = Vs[cur];

    // ---- S^T = K Q^T (swapped): lane gets S[q=fr][kv=n*16+fq*4+r]
    f32x4 sfr[4];
    __builtin_amdgcn_s_setprio(1);
#pragma unroll
    for (int n = 0; n < 4; ++n) {
      int krow = n * 16 + fr;
      bf16x8 kf0 = ldfrag(Kc + krow * 64 + ((fq * 8)      ^ ((krow & 7) << 3)));
      bf16x8 kf1 = ldfrag(Kc + krow * 64 + ((fq * 8 + 32) ^ ((krow & 7) << 3)));
      f32x4 z = {};
      z = __builtin_amdgcn_mfma_f32_16x16x32_bf16(kf0, qa0, z, 0, 0, 0);
      z = __builtin_amdgcn_mfma_f32_16x16x32_bf16(kf1, qa1, z, 0, 0, 0);
      sfr[n] = z;
    }
    __builtin_amdgcn_s_setprio(0);

    // ---- p = exp2(s); mask on peeled diagonal tile; pack to bf16 pairs
    uint32_t W[4][2];
#pragma unroll
    for (int n = 0; n < 4; ++n) {
      float p0, p1, p2, p3;
      if (kb < qb) {
        p0 = exp2f(sfr[n][0]);
        p1 = exp2f(sfr[n][1]);
        p2 = exp2f(sfr[n][2]);
        p3 = exp2f(sfr[n][3]);
      } else {
        int kvg = kb * 64 + n * 16 + fq * 4;
        p0 = (kvg + 0 > qrow) ? 0.f : exp2f(sfr[n][0]);
        p1 = (kvg + 1 > qrow) ? 0.f : exp2f(sfr[n][1]);
        p2 = (kvg + 2 > qrow) ? 0.f : exp2f(sfr[n][2]);
        p3 = (kvg + 3 > qrow) ? 0.f : exp2f(sfr[n][3]);
      }
      ssum += (p0 + p1) + (p2 + p3);
      W[n][0] = cvt_pk_bf16(p0, p1);
      W[n][1] = cvt_pk_bf16(p2, p3);
    }

    // ---- in-register P redistribution: (swap32 then swap16) per (n-pair, h)
    // After: lane(fq,fr) holds P[q=fr][kv=8fq+0..7] (pa0), [+32..39] (pa1).
    union { uint32_t u[4]; bf16x8 v; } pa0u, pa1u;
#pragma unroll
    for (int hh = 0; hh < 2; ++hh) {
      uint32_t a0 = W[0][hh], b0 = W[1][hh];
      asm("v_permlane32_swap_b32 %0, %1" : "+v"(a0), "+v"(b0));
      asm("v_permlane16_swap_b32 %0, %1" : "+v"(a0), "+v"(b0));
      pa0u.u[hh] = a0; pa0u.u[2 + hh] = b0;
      uint32_t a1 = W[2][hh], b1 = W[3][hh];
      asm("v_permlane32_swap_b32 %0, %1" : "+v"(a1), "+v"(b1));
      asm("v_permlane16_swap_b32 %0, %1" : "+v"(a1), "+v"(b1));
      pa1u.u[hh] = a1; pa1u.u[2 + hh] = b1;
    }

    // ---- O += P V : swizzled V^T reads; P from registers
    __builtin_amdgcn_s_setprio(1);
#pragma unroll
    for (int nh = 0; nh < 4; ++nh) {
      int vrow = nh * 16 + fr;
      bf16x8 vb0 = ldfrag(Vc + vrow * 64 + ((fq * 8)      ^ ((vrow & 7) << 3)));
      bf16x8 vb1 = ldfrag(Vc + vrow * 64 + ((fq * 8 + 32) ^ ((vrow & 7) << 3)));
      accO[nh] = __builtin_amdgcn_mfma_f32_16x16x32_bf16(pa0u.v, vb0, accO[nh], 0, 0, 0);
      accO[nh] = __builtin_amdgcn_mfma_f32_16x16x32_bf16(pa1u.v, vb1, accO[nh], 0, 0, 0);
    }
    __builtin_amdgcn_s_setprio(0);
    cur ^= 1;
  }

  // ---- finalize: sum the 4 fq copies of q=fr, invert, redistribute
  ssum += __shfl_xor(ssum, 16);
  ssum += __shfl_xor(ssum, 32);
  float inv = 1.0f / ssum;           // for q-row = fr
  float invq[4];
#pragma unroll
  for (int r = 0; r < 4; ++r) invq[r] = __shfl(inv, fq * 4 + r);   // q = fq*4+r

  // ---- epilogue: O[q=fq*4+r][hd=nh*16+fr], write bf16 [b,s,(h,hd)]
#pragma unroll
  for (int nh = 0; nh < 4; ++nh)
#pragma unroll
    for (int r = 0; r < 4; ++r) {
      float o = accO[nh][r] * invq[r];
      int qr = q0 + wid * 16 + fq * 4 + r;
      Ow[((size_t)b * 2048 + qr) * 1024 + h * 64 + nh * 16 + fr] = f2bf(o);
    }
}

// ---------------------------------------------------------------------------
// Output projection: O[4096][1024] x Wo[1024][1024]^T + b -> y fp32
// ---------------------------------------------------------------------------
__global__ __launch_bounds__(256) void proj_gemm_kernel(
    const u16* __restrict__ Ob, const u16* __restrict__ Wob,
    const float* __restrict__ bias, float* __restrict__ out) {
  __shared__ u16 As[128 * 32];
  __shared__ u16 Bs[128 * 32];
  const int NB = 8;
  int m0 = (blockIdx.x / NB) * 128, n0 = (blockIdx.x % NB) * 128;
  f32x4 acc[4][4] = {};
  gemm128_core(Ob, Wob, m0, n0, 1024, As, Bs, acc);

  const int lane = threadIdx.x & 63, wid = threadIdx.x >> 6;
  const int wr = wid >> 1, wc = wid & 1, fq = lane >> 4, fr = lane & 15;
#pragma unroll
  for (int i = 0; i < 4; ++i)
#pragma unroll
    for (int j = 0; j < 4; ++j)
#pragma unroll
      for (int r = 0; r < 4; ++r) {
        int m = m0 + wr * 64 + i * 16 + fq * 4 + r;
        int n = n0 + wc * 64 + j * 16 + fr;
        out[(size_t)m * 1024 + n] = acc[i][j][r] + bias[n];
      }
}

// ---------------------------------------------------------------------------
extern "C" void kernel_launch(void* const* d_in, const int* in_sizes, int n_in,
                              void* d_out, int out_size, void* d_ws, size_t ws_size,
                              hipStream_t stream) {
  const float* x    = (const float*)d_in[0];
  const float* wqkv = (const float*)d_in[1];
  const float* wo   = (const float*)d_in[2];
  const float* wo_b = (const float*)d_in[3];
  float* out = (float*)d_out;

  u16* xb    = (u16*)d_ws;            // 4096*1024
  u16* wqkvb = xb    + 4194304;       // 3072*1024
  u16* wob   = wqkvb + 3145728;       // 1024*1024
  u16* q_ws  = wob   + 1048576;       // [2,16,2048,64] (pre-scaled)
  u16* k_ws  = q_ws  + 4194304;       // [2,16,2048,64]
  u16* vt_ws = k_ws  + 4194304;       // [2,16,64,2048]  (V^T)
  u16* o_ws  = vt_ws + 4194304;       // [4096,1024]

  static bool attr_set = false;
  if (!attr_set) {
    hipFuncSetAttribute((const void*)qkv_gemm_kernel,
                        hipFuncAttributeMaxDynamicSharedMemorySize, 131072);
    attr_set = true;
  }

  cvt_all<<<2048, 256, 0, stream>>>(x, wqkv, wo, xb, wqkvb, wob);
  qkv_gemm_kernel<<<192, 512, 131072, stream>>>(xb, wqkvb, q_ws, k_ws, vt_ws, out);
  attn_kernel<<<32 * 32, 256, 0, stream>>>(q_ws, k_ws, vt_ws, o_ws);
  proj_gemm_kernel<<<32 * 8, 256, 0, stream>>>(o_ws, wob, wo_b, out);
}